// Round 2
// baseline (362.258 us; speedup 1.0000x reference)
//
#include <hip/hip_runtime.h>

#define MARGIN 0.5f

// x: [V, C, T] fp32, T=128 contiguous. target: [V, C] int.
// Half-wave (32 lanes) per row, float4/lane (512 B coalesced per half-wave).
// Sum max(0, x - pos + margin) over ALL t; the t==target term is exactly
// MARGIN, subtracted once per row. Unrolled x4: all loads issued before any
// dependent use, to keep 8 memory ops in flight per wave.

__device__ __forceinline__ float sel_comp(float4 v, int tgt) {
    float lo = (tgt & 1) ? v.y : v.x;
    float hi = (tgt & 1) ? v.w : v.z;
    return (tgt & 2) ? hi : lo;
}

__device__ __forceinline__ float hinge4(float4 v, float pos) {
    const float b = MARGIN - pos;
    return fmaxf(v.x + b, 0.0f) + fmaxf(v.y + b, 0.0f)
         + fmaxf(v.z + b, 0.0f) + fmaxf(v.w + b, 0.0f);
}

__global__ __launch_bounds__(256) void margin_loss_kernel(
    const float* __restrict__ x,
    const int* __restrict__ target,
    float* __restrict__ out,
    int rows,          // V*C
    float inv_cnt)     // 1 / (V*C*(T-1))
{
    const int T = 128;
    const int tid = threadIdx.x;
    const int lane = tid & 63;          // lane in wave (wave64)
    const int wave = tid >> 6;          // wave in block: 0..3
    const int gl = lane & 31;           // lane within half-wave group
    const int group = lane >> 5;        // which half-wave (0/1)
    const int bcast = group << 5;       // shfl base lane for this half-wave

    const int slot = ((blockIdx.x * 4 + wave) << 1) + group;
    const int stride = gridDim.x * 8;   // total half-wave slots

    float acc = 0.0f;
    int nrows = 0;
    int row = slot;

    // main loop: 4 rows per iteration, loads batched for MLP
    for (; row + 3 * stride < rows; row += 4 * stride) {
        const int r0 = row, r1 = row + stride, r2 = row + 2 * stride, r3 = row + 3 * stride;
        const float4 v0 = ((const float4*)(x + (size_t)r0 * T))[gl];
        const float4 v1 = ((const float4*)(x + (size_t)r1 * T))[gl];
        const float4 v2 = ((const float4*)(x + (size_t)r2 * T))[gl];
        const float4 v3 = ((const float4*)(x + (size_t)r3 * T))[gl];
        const int t0 = target[r0];
        const int t1 = target[r1];
        const int t2 = target[r2];
        const int t3 = target[r3];

        const float p0 = __shfl(sel_comp(v0, t0), bcast + (t0 >> 2), 64);
        const float p1 = __shfl(sel_comp(v1, t1), bcast + (t1 >> 2), 64);
        const float p2 = __shfl(sel_comp(v2, t2), bcast + (t2 >> 2), 64);
        const float p3 = __shfl(sel_comp(v3, t3), bcast + (t3 >> 2), 64);

        acc += hinge4(v0, p0) + hinge4(v1, p1)
             + hinge4(v2, p2) + hinge4(v3, p3);
        nrows += 4;
    }
    // tail
    for (; row < rows; row += stride) {
        const float4 v = ((const float4*)(x + (size_t)row * T))[gl];
        const int tgt = target[row];
        const float p = __shfl(sel_comp(v, tgt), bcast + (tgt >> 2), 64);
        acc += hinge4(v, p);
        nrows += 1;
    }

    // remove the t==target term (exactly MARGIN per row)
    if (gl == 0) acc -= MARGIN * (float)nrows;

    // wave reduction (64 lanes)
    #pragma unroll
    for (int off = 32; off > 0; off >>= 1)
        acc += __shfl_down(acc, off, 64);

    __shared__ float s[4];
    if (lane == 0) s[wave] = acc;
    __syncthreads();
    if (tid == 0) {
        float total = (s[0] + s[1]) + (s[2] + s[3]);
        atomicAdd(out, total * inv_cnt);
    }
}

extern "C" void kernel_launch(void* const* d_in, const int* in_sizes, int n_in,
                              void* d_out, int out_size, void* d_ws, size_t ws_size,
                              hipStream_t stream) {
    const float* x = (const float*)d_in[0];
    const int* target = (const int*)d_in[1];
    float* out = (float*)d_out;

    const int T = 128;
    const int rows = in_sizes[1];              // V*C = 524288
    const long long cnt = (long long)rows * (T - 1);
    const float inv_cnt = 1.0f / (float)cnt;

    hipMemsetAsync(out, 0, sizeof(float), stream);

    const int blocks = 2048;                   // 16384 half-wave slots, 32 rows each
    margin_loss_kernel<<<blocks, 256, 0, stream>>>(x, target, out, rows, inv_cnt);
}